// Round 9
// baseline (92.712 us; speedup 1.0000x reference)
//
#include <hip/hip_runtime.h>
#include <hip/hip_bf16.h>

// EvoAttn: causal self-attention with Q=K=V = x.reshape(B,L,H,D).
// B=2 H=16 L=2048 D=128, fp32 in/out, bf16 MFMA compute.
// v9 = v8 (balanced pair scheduling) + ALL LDS accesses linear fragment-order:
//      K prepacked per-fragment like V; P stored [k-octet][q15]. No swizzles,
//      no runtime XOR address math, conflict-free ds_read_b128 everywhere.

#define TL 2048
#define TE 2048
#define TD 128
#define KB 64
#define NTILES 32                          // TL / KB
#define TILE_B 16384                       // 64*128*2 bytes
#define KV_REGION (32 * NTILES * TILE_B)   // 16 MB per layout
#define WS_NEED (2u * (unsigned)KV_REGION) // 32 MB

typedef __attribute__((ext_vector_type(8))) short bf16x8;
typedef __attribute__((ext_vector_type(4))) float f32x4;
typedef __attribute__((ext_vector_type(8))) unsigned short u16x8;
typedef __attribute__((ext_vector_type(4))) unsigned short u16x4;

// (1/sqrt(128)) * log2(e)
#define SCALE_LOG2E 0.12751879f

__device__ __forceinline__ unsigned short f2bf(float f) {
  __hip_bfloat16 h = __float2bfloat16(f);
  return __builtin_bit_cast(unsigned short, h);
}

__device__ __forceinline__ f32x4 mfma16(bf16x8 a, bf16x8 b, f32x4 c) {
  return __builtin_amdgcn_mfma_f32_16x16x32_bf16(a, b, c, 0, 0, 0);
}

__device__ __forceinline__ void gl_lds16(const void* g, void* l) {
  __builtin_amdgcn_global_load_lds(
      (__attribute__((address_space(1))) void*)(g),
      (__attribute__((address_space(3))) void*)(l), 16, 0, 0);
}

// ws layout:
// K region: per-tile FRAGMENT-ORDER K: 16B frag (kt2,c,g,q15) at byte
//   ((kt2*4+c)*64 + g*16 + q15)*16 holding K[kt2*16+q15][c*32+g*8 .. +8).
// V region: per-tile FRAGMENT-ORDER V: 16B frag (half,dt,g,q15) at byte
//   ((half*8+dt)*64 + g*16 + q15)*16 holding V[k=half*32+g*8+j][d=dt*16+q15].
__global__ void __launch_bounds__(256)
prepack(const float* __restrict__ x, char* __restrict__ wsb) {
  const int bid = blockIdx.x;            // bh*32 + kt
  const int kt = bid & 31;
  const int bh = bid >> 5;
  const int b = bh >> 4;
  const int h = bh & 15;
  const float* src = x + (size_t)b * TL * TE + h * TD + (size_t)kt * KB * TE;
  const int t = threadIdx.x;
  const int kr = (t >> 4) << 2;          // 4 consecutive k-rows
  const int d0 = (t & 15) << 3;          // 8 d-cols = one (c,g) chunk
  unsigned short c[4][8];
#pragma unroll
  for (int rr = 0; rr < 4; ++rr) {
    const float* p = src + (kr + rr) * TE + d0;
    const float4 a = *(const float4*)p;
    const float4 bb = *(const float4*)(p + 4);
    c[rr][0] = f2bf(a.x);  c[rr][1] = f2bf(a.y);  c[rr][2] = f2bf(a.z);  c[rr][3] = f2bf(a.w);
    c[rr][4] = f2bf(bb.x); c[rr][5] = f2bf(bb.y); c[rr][6] = f2bf(bb.z); c[rr][7] = f2bf(bb.w);
  }
  // K fragment order: this thread's 8 cols are exactly chunk (cc_, gg_)
  char* gkv = wsb + (size_t)bid * TILE_B;
  const int kt2 = kr >> 4;
  const int q0r = kr & 15;
  const int cc_ = (t & 15) >> 2;         // d0 / 32
  const int gg_ = (t & 15) & 3;          // (d0 % 32) / 8
#pragma unroll
  for (int rr = 0; rr < 4; ++rr) {
    u16x8 o = {c[rr][0], c[rr][1], c[rr][2], c[rr][3],
               c[rr][4], c[rr][5], c[rr][6], c[rr][7]};
    const int off = (((kt2 * 4 + cc_) * 64 + gg_ * 16 + (q0r + rr)) << 4);
    *(u16x8*)(gkv + off) = o;
  }
  // V fragment order
  char* gkt = wsb + KV_REGION + (size_t)bid * TILE_B;
  const int half = kr >> 5;
  const int g = (kr >> 3) & 3;
  const int j0 = kr & 7;                 // 0 or 4
#pragma unroll
  for (int cc = 0; cc < 8; ++cc) {
    const int d = d0 + cc;
    u16x4 o = {c[0][cc], c[1][cc], c[2][cc], c[3][cc]};   // k = kr..kr+3
    const int off = (((half * 8 + (d >> 4)) * 64 + g * 16 + (d & 15)) << 4) + j0 * 2;
    *(u16x4*)(gkt + off) = o;
  }
}

// ---------------- main attention kernel: pair (a, 31-a), 33 steps/block -----
__global__ void __launch_bounds__(256)
evo_attn2(const char* __restrict__ wsb, float* __restrict__ out) {
  // kv0 | kv1 | kvt | pl(4 waves x 2KB) = 56 KB -> 2 blocks/CU
  __shared__ char smem[3 * TILE_B + 8192];

  const int t = threadIdx.x;
  const int lane = t & 63;
  const int w = t >> 6;        // wave 0..3, owns q rows [q0+16w, q0+16w+16)
  const int g = lane >> 4;
  const int q15 = lane & 15;

  const int blk = blockIdx.x;            // 512 blocks
  // XCD-affine: xcd = blk&7 serves bh in {4*xcd .. 4*xcd+3}
  const int bh = (blk & 7) * 4 + (blk >> 7);
  const int a = (blk >> 3) & 15;         // pair index: q-tiles a and 31-a
  const int b = bh >> 4;
  const int h = bh & 15;

  const char* gkv = wsb + (size_t)bh * (NTILES * TILE_B);
  const char* gkt = wsb + KV_REGION + (size_t)bh * (NTILES * TILE_B);
  char* plw = smem + 3 * TILE_B + w * 2048;
  const char* kvtb = smem + 2 * TILE_B;
  const int l16 = lane * 16;

#define STAGE_KV(BUFI, KT)                                                 \
  {                                                                        \
    char* dst_ = smem + (BUFI) * TILE_B + (t >> 6) * 1024;                 \
    const char* src_ = gkv + (size_t)(KT) * TILE_B + t * 16;               \
    _Pragma("unroll")                                                      \
    for (int i_ = 0; i_ < 4; ++i_) gl_lds16(src_ + i_ * 4096, dst_ + i_ * 4096); \
  }
#define STAGE_KVT(KT)                                                      \
  {                                                                        \
    char* dst_ = smem + 2 * TILE_B + (t >> 6) * 1024;                      \
    const char* src_ = gkt + (size_t)(KT) * TILE_B + t * 16;               \
    _Pragma("unroll")                                                      \
    for (int i_ = 0; i_ < 4; ++i_) gl_lds16(src_ + i_ * 4096, dst_ + i_ * 4096); \
  }

#pragma unroll 1
  for (int seg = 0; seg < 2; ++seg) {
    const int qt = seg ? (31 - a) : a;   // q-tile index, rows [64qt, 64qt+64)
    const int nt = qt + 1;               // tiles: s=0 diag(qt), s>0 -> s-1

    // prologue: diag kv + kv tile 0 + diag kvt
    STAGE_KV(0, qt);
    if (nt > 1) STAGE_KV(1, 0);
    STAGE_KVT(qt);
    asm volatile("s_waitcnt vmcnt(0)" ::: "memory");
    __builtin_amdgcn_s_barrier();
    asm volatile("" ::: "memory");

    // Q fragments from buf0 (the diagonal tile IS the Q tile); kt2 = w
    bf16x8 qf[4];
#pragma unroll
    for (int c = 0; c < 4; ++c)
      qf[c] = *(const bf16x8*)(smem + (w * 4 + c) * 1024 + l16);

    f32x4 acc[8];
#pragma unroll
    for (int dt = 0; dt < 8; ++dt) acc[dt] = (f32x4){0.f, 0.f, 0.f, 0.f};
    float mrun = -1e30f;   // raw score domain
    float lrun = 0.f;

    for (int s = 0; s < nt; ++s) {
      if (s > 0) {  // kv(s) ready; queue <= [kvt(s):4, kv(s+1):4]
        asm volatile("s_waitcnt vmcnt(8)" ::: "memory");
        __builtin_amdgcn_s_barrier();
        asm volatile("" ::: "memory");
      }
      const char* kv = smem + (s & 1) * TILE_B;

      // QK^T: lane (g,q15) holds S[k=kt2*16+g*4+r][q=16w+q15] (raw)
      float sv[16];
      __builtin_amdgcn_s_setprio(1);
#pragma unroll
      for (int kt2 = 0; kt2 < 4; ++kt2) {
        f32x4 st = (f32x4){0.f, 0.f, 0.f, 0.f};
#pragma unroll
        for (int c = 0; c < 4; ++c) {
          bf16x8 kf = *(const bf16x8*)(kv + (kt2 * 4 + c) * 1024 + l16);
          st = mfma16(kf, qf[c], st);
        }
#pragma unroll
        for (int r = 0; r < 4; ++r) sv[kt2 * 4 + r] = st[r];
      }
      __builtin_amdgcn_s_setprio(0);

      if (s == 0) {  // diagonal causal mask
        const int qrel = 16 * w + q15;
#pragma unroll
        for (int kt2 = 0; kt2 < 4; ++kt2)
#pragma unroll
          for (int r = 0; r < 4; ++r)
            if (kt2 * 16 + g * 4 + r > qrel) sv[kt2 * 4 + r] = -1e30f;
      }

      // online softmax, defer-max fast path
      float m0 = fmaxf(fmaxf(sv[0], sv[1]), fmaxf(sv[2], sv[3]));
      float m1 = fmaxf(fmaxf(sv[4], sv[5]), fmaxf(sv[6], sv[7]));
      float m2 = fmaxf(fmaxf(sv[8], sv[9]), fmaxf(sv[10], sv[11]));
      float m3 = fmaxf(fmaxf(sv[12], sv[13]), fmaxf(sv[14], sv[15]));
      float tmax = fmaxf(fmaxf(m0, m1), fmaxf(m2, m3));
      tmax = fmaxf(tmax, __shfl_xor(tmax, 16));
      tmax = fmaxf(tmax, __shfl_xor(tmax, 32));

      float pf[16];
      if (__all(tmax <= mrun)) {
        const float nmc = -mrun * SCALE_LOG2E;
#pragma unroll
        for (int i = 0; i < 16; ++i) pf[i] = exp2f(fmaf(sv[i], SCALE_LOG2E, nmc));
      } else {
        const float mnew = fmaxf(mrun, tmax);
        const float al = exp2f((mrun - mnew) * SCALE_LOG2E);
        mrun = mnew;
        const float nmc = -mnew * SCALE_LOG2E;
#pragma unroll
        for (int i = 0; i < 16; ++i) pf[i] = exp2f(fmaf(sv[i], SCALE_LOG2E, nmc));
        lrun *= al;
        float ar[4];
#pragma unroll
        for (int r = 0; r < 4; ++r) ar[r] = __shfl(al, g * 4 + r);
#pragma unroll
        for (int dt = 0; dt < 8; ++dt)
#pragma unroll
          for (int r = 0; r < 4; ++r) acc[dt][r] *= ar[r];
      }
      {
        float s01 = (pf[0] + pf[1]) + (pf[2] + pf[3]);
        float s23 = (pf[4] + pf[5]) + (pf[6] + pf[7]);
        float s45 = (pf[8] + pf[9]) + (pf[10] + pf[11]);
        float s67 = (pf[12] + pf[13]) + (pf[14] + pf[15]);
        lrun += (s01 + s23) + (s45 + s67);
      }

      // P -> per-wave LDS as [k-octet m][q15] 16B units (conflict-free read).
      // Writer (g,q15): chunk kt2 (k=kt2*16+g*4..+3) is 8B of unit
      // (m = kt2*2+(g>>1), q15), half-select (g&1).
      {
        const int wb = q15 * 16 + (g & 1) * 8;
#pragma unroll
        for (int kt2 = 0; kt2 < 4; ++kt2) {
          u16x4 o = {f2bf(pf[kt2 * 4]), f2bf(pf[kt2 * 4 + 1]),
                     f2bf(pf[kt2 * 4 + 2]), f2bf(pf[kt2 * 4 + 3])};
          *(u16x4*)(plw + (kt2 * 2 + (g >> 1)) * 256 + wb) = o;
        }
      }
      asm volatile("s_waitcnt lgkmcnt(0)" ::: "memory");

      if (s > 0) {  // kvt(s) ready; leave kv(s+1):4 outstanding if staged
        if (s + 1 < nt) asm volatile("s_waitcnt vmcnt(4)" ::: "memory");
        else            asm volatile("s_waitcnt vmcnt(0)" ::: "memory");
        __builtin_amdgcn_s_barrier();
        asm volatile("" ::: "memory");
      }

      // PV: acc[dt] += P(16x64) * V(64x16 slice dt); all reads linear
      bf16x8 pa0 = *(const bf16x8*)(plw + g * 256 + q15 * 16);
      bf16x8 pa1 = *(const bf16x8*)(plw + (4 + g) * 256 + q15 * 16);
      __builtin_amdgcn_s_setprio(1);
#pragma unroll
      for (int dt = 0; dt < 8; ++dt) {
        bf16x8 vb0 = *(const bf16x8*)(kvtb + dt * 1024 + l16);
        bf16x8 vb1 = *(const bf16x8*)(kvtb + (8 + dt) * 1024 + l16);
        acc[dt] = mfma16(pa0, vb0, acc[dt]);
        acc[dt] = mfma16(pa1, vb1, acc[dt]);
      }
      __builtin_amdgcn_s_setprio(0);

      // all waves done reading kv(s)/kvt(s); refill
      __builtin_amdgcn_s_barrier();
      asm volatile("" ::: "memory");
      if (s + 1 < nt) STAGE_KVT(s);          // tile(s+1) = s
      if (s + 2 < nt) STAGE_KV(s & 1, s + 1);// tile(s+2) = s+1, buf (s+2)&1
    }

    // combine g-group partial sums, normalize, write out
    lrun += __shfl_xor(lrun, 16);
    lrun += __shfl_xor(lrun, 32);
    const float inv = 1.f / lrun;
    float ir[4];
#pragma unroll
    for (int r = 0; r < 4; ++r) ir[r] = __shfl(inv, g * 4 + r);

    float* ob = out + ((size_t)b * TL + qt * 64 + 16 * w) * TE + h * TD;
#pragma unroll
    for (int dt = 0; dt < 8; ++dt)
#pragma unroll
      for (int r = 0; r < 4; ++r)
        ob[(g * 4 + r) * TE + dt * 16 + q15] = acc[dt][r] * ir[r];

    __builtin_amdgcn_s_barrier();  // don't let seg-2 prologue race seg-1 reads
    asm volatile("" ::: "memory");
  }
}

// ---------------- fallback (v1-style, self-contained, no ws needed) ---------
__device__ __forceinline__ bf16x8 ld256s(const unsigned short* base, int row, int inrow) {
  const int off = (row * 256 + inrow) ^ ((row & 7) << 4);
  return *(const bf16x8*)((const char*)base + off);
}
__device__ __forceinline__ bf16x8 ld128s(const unsigned short* base, int row, int inrow) {
  const int off = (row * 128 + inrow) ^ ((row & 7) << 4);
  return *(const bf16x8*)((const char*)base + off);
}

__device__ __forceinline__ void stage_tile_fb(const float* __restrict__ src,
                                              unsigned short* kv, unsigned short* kvt,
                                              int t) {
  const int kr = (t >> 4) << 2;
  const int d0 = (t & 15) << 3;
  unsigned short c[4][8];
#pragma unroll
  for (int rr = 0; rr < 4; ++rr) {
    const float* p = src + (kr + rr) * TE + d0;
    const float4 a = *(const float4*)p;
    const float4 b = *(const float4*)(p + 4);
    c[rr][0] = f2bf(a.x); c[rr][1] = f2bf(a.y); c[rr][2] = f2bf(a.z); c[rr][3] = f2bf(a.w);
    c[rr][4] = f2bf(b.x); c[rr][5] = f2bf(b.y); c[rr][6] = f2bf(b.z); c[rr][7] = f2bf(b.w);
  }
#pragma unroll
  for (int rr = 0; rr < 4; ++rr) {
    const int r = kr + rr;
    u16x8 o = {c[rr][0], c[rr][1], c[rr][2], c[rr][3],
               c[rr][4], c[rr][5], c[rr][6], c[rr][7]};
    const int off = (r * 256 + d0 * 2) ^ ((r & 7) << 4);
    *(u16x8*)((char*)kv + off) = o;
  }
#pragma unroll
  for (int cc = 0; cc < 8; ++cc) {
    const int d = d0 + cc;
    u16x4 o = {c[0][cc], c[1][cc], c[2][cc], c[3][cc]};
    const int off = (d * 128 + kr * 2) ^ ((d & 7) << 4);
    *(u16x4*)((char*)kvt + off) = o;
  }
}

__global__ void __launch_bounds__(256)
evo_attn(const float* __restrict__ x, float* __restrict__ out) {
  __shared__ unsigned short kv[KB * TD];
  __shared__ unsigned short kvt[TD * KB];
  __shared__ unsigned short pl[4 * 16 * KB];

  const int t = threadIdx.x;
  const int lane = t & 63;
  const int w = t >> 6;
  const int g = lane >> 4;
  const int q15 = lane & 15;

  const int bh = blockIdx.x & 31;
  const int qt = 31 - (blockIdx.x >> 5);
  const int b = bh >> 4;
  const int h = bh & 15;
  const float* xb = x + (size_t)b * TL * TE + h * TD;
  const int q0 = qt * KB;

  stage_tile_fb(xb + (size_t)q0 * TE, kv, kvt, t);
  __syncthreads();

  bf16x8 qf[4];
#pragma unroll
  for (int c = 0; c < 4; ++c)
    qf[c] = ld256s(kv, 16 * w + q15, c * 64 + g * 16);

  f32x4 acc[8];
#pragma unroll
  for (int dt = 0; dt < 8; ++dt) acc[dt] = (f32x4){0.f, 0.f, 0.f, 0.f};
  float mrun = -1e30f;
  float lrun = 0.f;
  unsigned short* plw = pl + w * (16 * KB);

  for (int s = 0; s <= qt; ++s) {
    if (s > 0) {
      __syncthreads();
      stage_tile_fb(xb + (size_t)(s - 1) * KB * TE, kv, kvt, t);
      __syncthreads();
    }
    float sv[16];
#pragma unroll
    for (int kt2 = 0; kt2 < 4; ++kt2) {
      f32x4 st = (f32x4){0.f, 0.f, 0.f, 0.f};
#pragma unroll
      for (int c = 0; c < 4; ++c) {
        bf16x8 kf = ld256s(kv, kt2 * 16 + q15, c * 64 + g * 16);
        st = mfma16(kf, qf[c], st);
      }
#pragma unroll
      for (int r = 0; r < 4; ++r) sv[kt2 * 4 + r] = st[r] * SCALE_LOG2E;
    }
    if (s == 0) {
      const int qrel = 16 * w + q15;
#pragma unroll
      for (int kt2 = 0; kt2 < 4; ++kt2)
#pragma unroll
        for (int r = 0; r < 4; ++r)
          if (kt2 * 16 + g * 4 + r > qrel) sv[kt2 * 4 + r] = -1e30f;
    }
    float tmax = sv[0];
#pragma unroll
    for (int i = 1; i < 16; ++i) tmax = fmaxf(tmax, sv[i]);
    tmax = fmaxf(tmax, __shfl_xor(tmax, 16));
    tmax = fmaxf(tmax, __shfl_xor(tmax, 32));
    const float mnew = fmaxf(mrun, tmax);
    const float al = exp2f(mrun - mnew);
    mrun = mnew;
    float psum = 0.f;
    unsigned short pb[16];
#pragma unroll
    for (int i = 0; i < 16; ++i) {
      const float p = exp2f(sv[i] - mnew);
      psum += p;
      pb[i] = f2bf(p);
    }
    lrun = lrun * al + psum;
#pragma unroll
    for (int kt2 = 0; kt2 < 4; ++kt2) {
      u16x4 o = {pb[kt2 * 4], pb[kt2 * 4 + 1], pb[kt2 * 4 + 2], pb[kt2 * 4 + 3]};
      const int off = (q15 * 128 + kt2 * 32 + g * 8) ^ ((q15 & 7) << 4);
      *(u16x4*)((char*)plw + off) = o;
    }
    asm volatile("s_waitcnt lgkmcnt(0)" ::: "memory");
    float ar[4];
#pragma unroll
    for (int r = 0; r < 4; ++r) ar[r] = __shfl(al, g * 4 + r);
#pragma unroll
    for (int dt = 0; dt < 8; ++dt)
#pragma unroll
      for (int r = 0; r < 4; ++r) acc[dt][r] *= ar[r];
    bf16x8 pa0 = ld128s(plw, q15, g * 16);
    bf16x8 pa1 = ld128s(plw, q15, 64 + g * 16);
#pragma unroll
    for (int dt = 0; dt < 8; ++dt) {
      bf16x8 vb0 = ld128s(kvt, dt * 16 + q15, g * 16);
      bf16x8 vb1 = ld128s(kvt, dt * 16 + q15, 64 + g * 16);
      acc[dt] = mfma16(pa0, vb0, acc[dt]);
      acc[dt] = mfma16(pa1, vb1, acc[dt]);
    }
  }

  lrun += __shfl_xor(lrun, 16);
  lrun += __shfl_xor(lrun, 32);
  const float inv = 1.f / lrun;
  float ir[4];
#pragma unroll
  for (int r = 0; r < 4; ++r) ir[r] = __shfl(inv, g * 4 + r);
  float* ob = out + ((size_t)b * TL + q0 + 16 * w) * TE + h * TD;
#pragma unroll
  for (int dt = 0; dt < 8; ++dt)
#pragma unroll
    for (int r = 0; r < 4; ++r)
      ob[(g * 4 + r) * TE + dt * 16 + q15] = acc[dt][r] * ir[r];
}

extern "C" void kernel_launch(void* const* d_in, const int* in_sizes, int n_in,
                              void* d_out, int out_size, void* d_ws, size_t ws_size,
                              hipStream_t stream) {
  const float* x = (const float*)d_in[0];
  float* out = (float*)d_out;
  (void)in_sizes; (void)n_in; (void)out_size;
  if (ws_size >= (size_t)WS_NEED) {
    char* wsb = (char*)d_ws;
    prepack<<<dim3(1024), dim3(256), 0, stream>>>(x, wsb);
    evo_attn2<<<dim3(512), dim3(256), 0, stream>>>(wsb, out);
  } else {
    evo_attn<<<dim3(1024), dim3(256), 0, stream>>>(x, out);
  }
}